// Round 5
// baseline (210.882 us; speedup 1.0000x reference)
//
#include <hip/hip_runtime.h>
#include <cstdint>
#include <cstddef>

#define HH 512
#define WW 512
#define BB 64
#define RPW 8             // rows per wave-strip
#define STRIPS (HH / RPW) // 64

// ws layout:
//   bits   : uint8[2][BB][HH][64]  (bit j of byte l = boundary at col 8*l+j,
//            ROW-MASKED: rows with sum>=300 already zeroed)               = 4 MB
//   counter: unsigned long long
//
// Algebra: binary masks -> class-0 and class-1 boundaries are identical
// (maxpool(1-m)-minpool(1-m) == maxpool(m)-minpool(m)), so boundary_mask = 2*b',
// b' in {0,1}; loss = 4/N * popcount(bp' XOR bg') after remove_long_lines —
// exact in integers. Row removal uses ORIGINAL row sums (computed in-wave
// before masking); column removal uses row-masked bits — matches reference
// sequential order. -inf padding == window restriction: vertical via bounds
// skip, horizontal via edge clamp (duplication harmless for max/min).

__global__ __launch_bounds__(256, 8) void boundary_bits_kernel(
    const float* __restrict__ seg, const float* __restrict__ gt,
    uint8_t* __restrict__ bits,
    unsigned long long* __restrict__ counter)
{
    if (blockIdx.x == 0 && threadIdx.x == 0) *counter = 0ull;

    const int lane  = threadIdx.x & 63;
    const int wid   = blockIdx.x * 4 + (threadIdx.x >> 6); // 4 waves/block
    const int z     = wid >> 12;          // 4096 waves per input
    const int b     = (wid >> 6) & 63;
    const int strip = wid & 63;
    const int r0    = strip * RPW;

    const float* img = (z ? gt : seg) + (size_t)b * HH * WW;
    uint8_t* brow = bits + (((size_t)z * BB + b) * HH) * 64;

    float hmx[3][8], hmn[3][8];

    auto loadrow = [&](int slot, int g) {
        if (unsigned(g) < (unsigned)HH) {
            const float* p = img + (size_t)g * WW + lane * 8;
            float4 va = *(const float4*)p;
            float4 vb = *(const float4*)(p + 4);
            int sl = (lane == 0) ? 0 : lane - 1;
            int sr = (lane == 63) ? 63 : lane + 1;
            float lf = __shfl(vb.w, sl); lf = (lane == 0)  ? va.x : lf;
            float rt = __shfl(va.x, sr); rt = (lane == 63) ? vb.w : rt;
            float e[10] = {lf, va.x, va.y, va.z, va.w, vb.x, vb.y, vb.z, vb.w, rt};
            #pragma unroll
            for (int c = 0; c < 8; ++c) {
                hmx[slot][c] = fmaxf(fmaxf(e[c], e[c + 1]), e[c + 2]);
                hmn[slot][c] = fminf(fminf(e[c], e[c + 1]), e[c + 2]);
            }
        } else {
            #pragma unroll
            for (int c = 0; c < 8; ++c) { hmx[slot][c] = -1e30f; hmn[slot][c] = 1e30f; }
        }
    };

    loadrow(0, r0 - 1);
    loadrow(1, r0);
    #pragma unroll
    for (int q = 0; q < RPW; ++q) {
        const int sP = q % 3, sC = (q + 1) % 3, sN = (q + 2) % 3;
        loadrow(sN, r0 + q + 1);
        unsigned byte = 0;
        #pragma unroll
        for (int c = 0; c < 8; ++c) {
            float wmax = fmaxf(fmaxf(hmx[sP][c], hmx[sC][c]), hmx[sN][c]);
            float wmin = fminf(fminf(hmn[sP][c], hmn[sC][c]), hmn[sN][c]);
            byte |= (wmax - wmin > 0.5f) ? (1u << c) : 0u;
        }
        // original row sum via wave reduce, then apply row removal in place
        int rs = __popc(byte);
        #pragma unroll
        for (int off = 32; off; off >>= 1) rs += __shfl_xor(rs, off);
        byte = (rs >= 300) ? 0u : byte;
        brow[(size_t)(r0 + q) * 64 + lane] = (uint8_t)byte;
    }
}

__global__ __launch_bounds__(512) void colxor_kernel(
    const uint64_t* __restrict__ bits,
    unsigned long long* __restrict__ counter)
{
    const int b    = blockIdx.x;
    const int tid  = threadIdx.x;
    const int wave = tid >> 6, lane = tid & 63;

    __shared__ unsigned long long cmask[2][8];
    __shared__ int red[8];

    // phase 1: wave w owns word-group w (cols 64w..64w+63), both inputs
    const int w = wave;
    int cnt0 = 0, cnt1 = 0;
    #pragma unroll
    for (int z = 0; z < 2; ++z) {
        const uint64_t* bb = bits + ((size_t)z * BB + b) * HH * 8;
        #pragma unroll
        for (int k = 0; k < 8; ++k) {
            uint64_t word = bb[(size_t)(k * 64 + lane) * 8 + w]; // row k*64+lane
            #pragma unroll
            for (int c = 0; c < 64; ++c) {
                unsigned long long m = __ballot((word >> c) & 1ull);
                int pc = __popcll(m);            // uniform (sgpr) per wave
                if (lane == c) { if (z == 0) cnt0 += pc; else cnt1 += pc; }
            }
        }
    }
    // lane c holds colsum for col w*64+c
    unsigned long long km0 = __ballot(cnt0 < 300);
    unsigned long long km1 = __ballot(cnt1 < 300);
    if (lane == 0) { cmask[0][w] = km0; cmask[1][w] = km1; }
    __syncthreads();

    // phase 2: thread = row; masked XOR popcount
    const uint64_t* bp = bits + ((size_t)0 * BB + b) * HH * 8 + (size_t)tid * 8;
    const uint64_t* bg = bits + ((size_t)1 * BB + b) * HH * 8 + (size_t)tid * 8;
    int cnt = 0;
    #pragma unroll
    for (int w2 = 0; w2 < 8; ++w2) {
        cnt += (int)__popcll((bp[w2] & cmask[0][w2]) ^ (bg[w2] & cmask[1][w2]));
    }
    #pragma unroll
    for (int off = 32; off; off >>= 1) cnt += __shfl_down(cnt, off);
    if (lane == 0) red[wave] = cnt;
    __syncthreads();
    if (tid == 0) {
        int s = 0;
        #pragma unroll
        for (int v = 0; v < 8; ++v) s += red[v];
        atomicAdd(counter, (unsigned long long)s);
    }
}

__global__ void finalize_kernel(const unsigned long long* __restrict__ counter,
                                float* __restrict__ out)
{
    if (threadIdx.x == 0 && blockIdx.x == 0) {
        double v = (double)(*counter) * (4.0 / 16777216.0); // 4/N, N = 64*512*512
        out[0] = (float)v;
    }
}

extern "C" void kernel_launch(void* const* d_in, const int* in_sizes, int n_in,
                              void* d_out, int out_size, void* d_ws, size_t ws_size,
                              hipStream_t stream) {
    const float* seg = (const float*)d_in[0];
    const float* gt  = (const float*)d_in[1];
    float* out = (float*)d_out;

    uint8_t* ws = (uint8_t*)d_ws;
    const size_t bits_bytes = (size_t)2 * BB * HH * 64; // 4 MB
    uint8_t* bits = ws;
    unsigned long long* counter = (unsigned long long*)(ws + bits_bytes);

    // K1: 2 inputs * 64 batches * 64 strips = 8192 waves / 4 per block
    boundary_bits_kernel<<<2048, 256, 0, stream>>>(seg, gt, bits, counter);
    // K2: one block per batch (colmask + XOR count fused)
    colxor_kernel<<<BB, 512, 0, stream>>>((const uint64_t*)bits, counter);
    finalize_kernel<<<1, 1, 0, stream>>>(counter, out);
}

// Round 6
// 170.655 us; speedup vs baseline: 1.2357x; 1.2357x over previous
//
#include <hip/hip_runtime.h>
#include <cstdint>
#include <cstddef>

#define HH 512
#define WW 512
#define BB 64
#define RPW 16            // rows per wave-strip (vertical); wave covers 256 cols

// ws layout:
//   bits   : uint64[2][BB][HH][8]   = 4 MB, UNMASKED boundary bits.
//   Column<->bit mapping (self-consistent K1/K2): word W = 4*half + c (c=0..3),
//   bit k of word W = boundary at col 256*half + 4*k + c. Rowsum/XOR/AND are
//   layout-agnostic; colmask uses the same mapping on both sides.
//   counter: unsigned long long
//
// Algebra: binary masks -> class-0 and class-1 boundaries identical, so
// boundary_mask = 2*b', b' in {0,1}; loss = 4/N * popcount(bp' XOR bg') after
// remove_long_lines — exact integers. Row removal (original row sums) then
// column removal (on row-masked bits) matches reference sequential order.
// -inf padding == window restriction: vertical bounds skip, horizontal clamp.

__global__ __launch_bounds__(256, 8) void boundary_bits_kernel(
    const float* __restrict__ seg, const float* __restrict__ gt,
    uint64_t* __restrict__ bits,
    unsigned long long* __restrict__ counter)
{
    if (blockIdx.x == 0 && threadIdx.x == 0) *counter = 0ull;

    const int lane  = threadIdx.x & 63;
    const int wid   = blockIdx.x * 4 + (threadIdx.x >> 6); // 8192 waves
    const int z     = wid >> 12;          // input select
    const int b     = (wid >> 6) & 63;    // batch
    const int strip = (wid >> 1) & 31;    // 16-row strip
    const int half  = wid & 1;            // left/right 256 cols
    const int r0    = strip * RPW;
    const int c0    = half * 256;

    const float* img = (z ? gt : seg) + (size_t)b * HH * WW;
    uint64_t* brow = bits + ((size_t)z * BB + b) * HH * 8 + 4 * half;

    const int cl = (c0 == 0) ? 0 : c0 - 1;            // clamped left-halo col
    const int cr = (c0 + 256 >= WW) ? WW - 1 : c0 + 256; // clamped right-halo col

    float hmx[3][4], hmn[3][4];

    auto digest = [&](int slot, int g) {
        if (unsigned(g) < (unsigned)HH) {
            const float* rowp = img + (size_t)g * WW;
            float4 v = *(const float4*)(rowp + c0 + lane * 4);
            float ha = rowp[cl];                  // broadcast (1 line)
            float hb = rowp[cr];                  // broadcast (1 line)
            float lf = __shfl(v.w, lane - 1);
            float rt = __shfl(v.x, lane + 1);
            if (lane == 0)  lf = ha;              // clamp-correct via address clamp
            if (lane == 63) rt = hb;
            float e0 = lf, e1 = v.x, e2 = v.y, e3 = v.z, e4 = v.w, e5 = rt;
            hmx[slot][0] = fmaxf(fmaxf(e0, e1), e2);
            hmx[slot][1] = fmaxf(fmaxf(e1, e2), e3);
            hmx[slot][2] = fmaxf(fmaxf(e2, e3), e4);
            hmx[slot][3] = fmaxf(fmaxf(e3, e4), e5);
            hmn[slot][0] = fminf(fminf(e0, e1), e2);
            hmn[slot][1] = fminf(fminf(e1, e2), e3);
            hmn[slot][2] = fminf(fminf(e2, e3), e4);
            hmn[slot][3] = fminf(fminf(e3, e4), e5);
        } else {
            #pragma unroll
            for (int c = 0; c < 4; ++c) { hmx[slot][c] = -1e30f; hmn[slot][c] = 1e30f; }
        }
    };

    digest(0, r0 - 1);
    digest(1, r0);
    #pragma unroll
    for (int q = 0; q < RPW; ++q) {
        const int sP = q % 3, sC = (q + 1) % 3, sN = (q + 2) % 3;
        digest(sN, r0 + q + 1);
        uint64_t m0, m1, m2, m3;
        {
            float wmax, wmin;
            wmax = fmaxf(fmaxf(hmx[sP][0], hmx[sC][0]), hmx[sN][0]);
            wmin = fminf(fminf(hmn[sP][0], hmn[sC][0]), hmn[sN][0]);
            m0 = __ballot(wmax - wmin > 0.5f);
            wmax = fmaxf(fmaxf(hmx[sP][1], hmx[sC][1]), hmx[sN][1]);
            wmin = fminf(fminf(hmn[sP][1], hmn[sC][1]), hmn[sN][1]);
            m1 = __ballot(wmax - wmin > 0.5f);
            wmax = fmaxf(fmaxf(hmx[sP][2], hmx[sC][2]), hmx[sN][2]);
            wmin = fminf(fminf(hmn[sP][2], hmn[sC][2]), hmn[sN][2]);
            m2 = __ballot(wmax - wmin > 0.5f);
            wmax = fmaxf(fmaxf(hmx[sP][3], hmx[sC][3]), hmx[sN][3]);
            wmin = fminf(fminf(hmn[sP][3], hmn[sC][3]), hmn[sN][3]);
            m3 = __ballot(wmax - wmin > 0.5f);
        }
        uint64_t mv = m0;
        mv = (lane == 1) ? m1 : mv;
        mv = (lane == 2) ? m2 : mv;
        mv = (lane == 3) ? m3 : mv;
        if (lane < 4) brow[(size_t)(r0 + q) * 8 + lane] = mv;
    }
}

__global__ __launch_bounds__(512) void colxor_kernel(
    const uint64_t* __restrict__ bits,
    unsigned long long* __restrict__ counter)
{
    const int b    = blockIdx.x;
    const int tid  = threadIdx.x;          // = row
    const int wave = tid >> 6, lane = tid & 63;

    __shared__ uint64_t w0T[8][HH];        // [word][row], transposed: bank-friendly
    __shared__ uint64_t w1T[8][HH];
    __shared__ unsigned long long cmask[2][8];
    __shared__ int red[8];

    // phase A: row loads (coalesced 64B x2 per thread), rowhit, mask, stash
    const uint64_t* bp = bits + ((size_t)0 * BB + b) * HH * 8 + (size_t)tid * 8;
    const uint64_t* bg = bits + ((size_t)1 * BB + b) * HH * 8 + (size_t)tid * 8;
    uint64_t r0v[8], r1v[8];
    int s0 = 0, s1 = 0;
    #pragma unroll
    for (int i = 0; i < 8; ++i) { r0v[i] = bp[i]; s0 += (int)__popcll(r0v[i]); }
    #pragma unroll
    for (int i = 0; i < 8; ++i) { r1v[i] = bg[i]; s1 += (int)__popcll(r1v[i]); }
    const bool h0 = (s0 >= 300), h1 = (s1 >= 300);
    #pragma unroll
    for (int i = 0; i < 8; ++i) {
        r0v[i] = h0 ? 0ull : r0v[i];
        r1v[i] = h1 ? 0ull : r1v[i];
        w0T[i][tid] = r0v[i];
        w1T[i][tid] = r1v[i];
    }
    __syncthreads();

    // phase B: wave w owns word w; ballot-transpose colsums over 512 rows
    int c0n = 0, c1n = 0;
    #pragma unroll
    for (int k = 0; k < 8; ++k) {
        uint64_t wa = w0T[wave][k * 64 + lane];
        uint64_t wb = w1T[wave][k * 64 + lane];
        #pragma unroll
        for (int c = 0; c < 64; ++c) {
            int pa = (int)__popcll(__ballot((wa >> c) & 1ull));
            int pb = (int)__popcll(__ballot((wb >> c) & 1ull));
            if (lane == c) { c0n += pa; c1n += pb; }
        }
    }
    unsigned long long km0 = __ballot(c0n < 300);
    unsigned long long km1 = __ballot(c1n < 300);
    if (lane == 0) { cmask[0][wave] = km0; cmask[1][wave] = km1; }
    __syncthreads();

    // phase C: masked XOR popcount from registers
    int cnt = 0;
    #pragma unroll
    for (int w = 0; w < 8; ++w)
        cnt += (int)__popcll((r0v[w] & cmask[0][w]) ^ (r1v[w] & cmask[1][w]));
    #pragma unroll
    for (int off = 32; off; off >>= 1) cnt += __shfl_down(cnt, off);
    if (lane == 0) red[wave] = cnt;
    __syncthreads();
    if (tid == 0) {
        int s = 0;
        #pragma unroll
        for (int v = 0; v < 8; ++v) s += red[v];
        atomicAdd(counter, (unsigned long long)s);
    }
}

__global__ void finalize_kernel(const unsigned long long* __restrict__ counter,
                                float* __restrict__ out)
{
    if (threadIdx.x == 0 && blockIdx.x == 0) {
        double v = (double)(*counter) * (4.0 / 16777216.0); // 4/N, N = 64*512*512
        out[0] = (float)v;
    }
}

extern "C" void kernel_launch(void* const* d_in, const int* in_sizes, int n_in,
                              void* d_out, int out_size, void* d_ws, size_t ws_size,
                              hipStream_t stream) {
    const float* seg = (const float*)d_in[0];
    const float* gt  = (const float*)d_in[1];
    float* out = (float*)d_out;

    uint8_t* ws = (uint8_t*)d_ws;
    const size_t bits_bytes = (size_t)2 * BB * HH * 8 * sizeof(uint64_t); // 4 MB
    uint64_t* bits = (uint64_t*)ws;
    unsigned long long* counter = (unsigned long long*)(ws + bits_bytes);

    // K1: 2 inputs * 64 batches * 32 strips * 2 halves = 8192 waves / 4 per block
    boundary_bits_kernel<<<2048, 256, 0, stream>>>(seg, gt, bits, counter);
    // K2: one block per batch (rowhit + colmask + XOR count fused)
    colxor_kernel<<<BB, 512, 0, stream>>>(bits, counter);
    finalize_kernel<<<1, 1, 0, stream>>>(counter, out);
}

// Round 7
// 169.694 us; speedup vs baseline: 1.2427x; 1.0057x over previous
//
#include <hip/hip_runtime.h>
#include <cstdint>
#include <cstddef>

#define HH 512
#define WW 512
#define BB 64
#define RPW 16            // rows per wave-strip (vertical); wave covers 256 cols

// ws layout:
//   bits   : uint64[2][BB][HH][8]   = 4 MB, UNMASKED boundary bits.
//   Column<->bit mapping (self-consistent K1/K2): word W = 4*half + c (c=0..3),
//   bit k of word W = boundary at col 256*half + 4*k + c. Rowsum/XOR/AND are
//   layout-agnostic; colmask uses the same mapping on both sides.
//   counter: unsigned long long
//
// Algebra: binary masks -> class-0 and class-1 boundaries identical, so
// boundary_mask = 2*b', b' in {0,1}; loss = 4/N * popcount(bp' XOR bg') after
// remove_long_lines — exact integers. Row removal (original row sums) then
// column removal (on row-masked bits) matches reference sequential order.
// -inf padding == window restriction == index CLAMP for max/min pooling
// (clamped duplicate is an in-window value): applied vertically AND
// horizontally, fully branchless.

__global__ __launch_bounds__(256, 8) void boundary_bits_kernel(
    const float* __restrict__ seg, const float* __restrict__ gt,
    uint64_t* __restrict__ bits,
    unsigned long long* __restrict__ counter)
{
    if (blockIdx.x == 0 && threadIdx.x == 0) *counter = 0ull;

    const int lane  = threadIdx.x & 63;
    const int wid   = blockIdx.x * 4 + (threadIdx.x >> 6); // 8192 waves
    const int z     = wid >> 12;          // input select
    const int b     = (wid >> 6) & 63;    // batch
    const int strip = (wid >> 1) & 31;    // 16-row strip
    const int half  = wid & 1;            // left/right 256 cols
    const int r0    = strip * RPW;
    const int c0    = half * 256;

    const float* img = (z ? gt : seg) + (size_t)b * HH * WW;
    uint64_t* brow = bits + ((size_t)z * BB + b) * HH * 8 + 4 * half;

    // single true broadcast column per row: inner edge of this half
    const int eoff = half ? 255 : 256;    // col index within the row

    float4 vq[4];      // 4-deep row queue (main 4 cols/lane)
    float  eq[4];      // matching inner-edge broadcast value

    auto issue = [&](int slot, int g) {
        int gc = g < 0 ? 0 : (g > HH - 1 ? HH - 1 : g);   // vertical clamp
        const float* rp = img + (size_t)gc * WW;
        vq[slot] = *(const float4*)(rp + c0 + lane * 4);
        eq[slot] = rp[eoff];
    };

    float hmx[3][4], hmn[3][4];

    auto digest = [&](int hs, int qs) {
        float4 v = vq[qs];
        float lf = __shfl(v.w, lane - 1);
        float rt = __shfl(v.x, lane + 1);
        // horizontal clamp at the image edge; broadcast at the half seam
        if (lane == 0)  lf = half ? eq[qs] : v.x;
        if (lane == 63) rt = half ? v.w    : eq[qs];
        float e0 = lf, e1 = v.x, e2 = v.y, e3 = v.z, e4 = v.w, e5 = rt;
        hmx[hs][0] = fmaxf(fmaxf(e0, e1), e2);
        hmx[hs][1] = fmaxf(fmaxf(e1, e2), e3);
        hmx[hs][2] = fmaxf(fmaxf(e2, e3), e4);
        hmx[hs][3] = fmaxf(fmaxf(e3, e4), e5);
        hmn[hs][0] = fminf(fminf(e0, e1), e2);
        hmn[hs][1] = fminf(fminf(e1, e2), e3);
        hmn[hs][2] = fminf(fminf(e2, e3), e4);
        hmn[hs][3] = fminf(fminf(e3, e4), e5);
    };

    // prologue: fill queue with rows r0-1 .. r0+2, digest the first two
    issue(0, r0 - 1);
    issue(1, r0);
    issue(2, r0 + 1);
    issue(3, r0 + 2);
    digest(0, 0);   // row r0-1
    digest(1, 1);   // row r0

    #pragma unroll
    for (int q = 0; q < RPW; ++q) {
        const int sP = q % 3, sC = (q + 1) % 3, sN = (q + 2) % 3;
        digest(sN, (q + 2) & 3);        // row r0+q+1 (loaded >=2 iters ago)
        issue(q & 3, r0 + q + 3);       // prefetch row r0+q+3 (slot free since q-2)
        uint64_t m0, m1, m2, m3;
        {
            float wmax, wmin;
            wmax = fmaxf(fmaxf(hmx[sP][0], hmx[sC][0]), hmx[sN][0]);
            wmin = fminf(fminf(hmn[sP][0], hmn[sC][0]), hmn[sN][0]);
            m0 = __ballot(wmax - wmin > 0.5f);
            wmax = fmaxf(fmaxf(hmx[sP][1], hmx[sC][1]), hmx[sN][1]);
            wmin = fminf(fminf(hmn[sP][1], hmn[sC][1]), hmn[sN][1]);
            m1 = __ballot(wmax - wmin > 0.5f);
            wmax = fmaxf(fmaxf(hmx[sP][2], hmx[sC][2]), hmx[sN][2]);
            wmin = fminf(fminf(hmn[sP][2], hmn[sC][2]), hmn[sN][2]);
            m2 = __ballot(wmax - wmin > 0.5f);
            wmax = fmaxf(fmaxf(hmx[sP][3], hmx[sC][3]), hmx[sN][3]);
            wmin = fminf(fminf(hmn[sP][3], hmn[sC][3]), hmn[sN][3]);
            m3 = __ballot(wmax - wmin > 0.5f);
        }
        uint64_t mv = m0;
        mv = (lane == 1) ? m1 : mv;
        mv = (lane == 2) ? m2 : mv;
        mv = (lane == 3) ? m3 : mv;
        if (lane < 4) brow[(size_t)(r0 + q) * 8 + lane] = mv;
    }
}

__global__ __launch_bounds__(512) void colxor_kernel(
    const uint64_t* __restrict__ bits,
    unsigned long long* __restrict__ counter)
{
    const int b    = blockIdx.x;
    const int tid  = threadIdx.x;          // = row
    const int wave = tid >> 6, lane = tid & 63;

    __shared__ uint64_t w0T[8][HH];        // [word][row]
    __shared__ uint64_t w1T[8][HH];
    __shared__ unsigned long long cmask[2][8];
    __shared__ int red[8];

    // phase A: row loads (coalesced 64B x2 per thread), rowhit, mask, stash
    const uint64_t* bp = bits + ((size_t)0 * BB + b) * HH * 8 + (size_t)tid * 8;
    const uint64_t* bg = bits + ((size_t)1 * BB + b) * HH * 8 + (size_t)tid * 8;
    uint64_t r0v[8], r1v[8];
    int s0 = 0, s1 = 0;
    #pragma unroll
    for (int i = 0; i < 8; ++i) { r0v[i] = bp[i]; s0 += (int)__popcll(r0v[i]); }
    #pragma unroll
    for (int i = 0; i < 8; ++i) { r1v[i] = bg[i]; s1 += (int)__popcll(r1v[i]); }
    const bool h0 = (s0 >= 300), h1 = (s1 >= 300);
    #pragma unroll
    for (int i = 0; i < 8; ++i) {
        r0v[i] = h0 ? 0ull : r0v[i];
        r1v[i] = h1 ? 0ull : r1v[i];
        w0T[i][tid] = r0v[i];
        w1T[i][tid] = r1v[i];
    }
    __syncthreads();

    // phase B: wave w owns word w; ballot-transpose colsums over 512 rows
    int c0n = 0, c1n = 0;
    #pragma unroll
    for (int k = 0; k < 8; ++k) {
        uint64_t wa = w0T[wave][k * 64 + lane];
        uint64_t wb = w1T[wave][k * 64 + lane];
        #pragma unroll
        for (int c = 0; c < 64; ++c) {
            int pa = (int)__popcll(__ballot((wa >> c) & 1ull));
            int pb = (int)__popcll(__ballot((wb >> c) & 1ull));
            if (lane == c) { c0n += pa; c1n += pb; }
        }
    }
    unsigned long long km0 = __ballot(c0n < 300);
    unsigned long long km1 = __ballot(c1n < 300);
    if (lane == 0) { cmask[0][wave] = km0; cmask[1][wave] = km1; }
    __syncthreads();

    // phase C: masked XOR popcount from registers
    int cnt = 0;
    #pragma unroll
    for (int w = 0; w < 8; ++w)
        cnt += (int)__popcll((r0v[w] & cmask[0][w]) ^ (r1v[w] & cmask[1][w]));
    #pragma unroll
    for (int off = 32; off; off >>= 1) cnt += __shfl_down(cnt, off);
    if (lane == 0) red[wave] = cnt;
    __syncthreads();
    if (tid == 0) {
        int s = 0;
        #pragma unroll
        for (int v = 0; v < 8; ++v) s += red[v];
        atomicAdd(counter, (unsigned long long)s);
    }
}

__global__ void finalize_kernel(const unsigned long long* __restrict__ counter,
                                float* __restrict__ out)
{
    if (threadIdx.x == 0 && blockIdx.x == 0) {
        double v = (double)(*counter) * (4.0 / 16777216.0); // 4/N, N = 64*512*512
        out[0] = (float)v;
    }
}

extern "C" void kernel_launch(void* const* d_in, const int* in_sizes, int n_in,
                              void* d_out, int out_size, void* d_ws, size_t ws_size,
                              hipStream_t stream) {
    const float* seg = (const float*)d_in[0];
    const float* gt  = (const float*)d_in[1];
    float* out = (float*)d_out;

    uint8_t* ws = (uint8_t*)d_ws;
    const size_t bits_bytes = (size_t)2 * BB * HH * 8 * sizeof(uint64_t); // 4 MB
    uint64_t* bits = (uint64_t*)ws;
    unsigned long long* counter = (unsigned long long*)(ws + bits_bytes);

    // K1: 2 inputs * 64 batches * 32 strips * 2 halves = 8192 waves / 4 per block
    boundary_bits_kernel<<<2048, 256, 0, stream>>>(seg, gt, bits, counter);
    // K2: one block per batch (rowhit + colmask + XOR count fused)
    colxor_kernel<<<BB, 512, 0, stream>>>(bits, counter);
    finalize_kernel<<<1, 1, 0, stream>>>(counter, out);
}

// Round 8
// 167.793 us; speedup vs baseline: 1.2568x; 1.0113x over previous
//
#include <hip/hip_runtime.h>
#include <cstdint>
#include <cstddef>

#define HH 512
#define WW 512
#define BB 64
#define RPW 16            // rows per wave-strip (vertical); wave covers 256 cols

// ws layout:
//   bits   : uint64[2][BB][HH][8]   = 4 MB, UNMASKED boundary bits.
//   Column<->bit mapping (self-consistent K1/K2): word W = 4*half + c (c=0..3),
//   bit k of word W = boundary at col 256*half + 4*k + c. Rowsum/XOR/AND are
//   layout-agnostic; colmask uses the same mapping on both sides.
//   counter: unsigned long long
//
// Algebra: binary masks -> class-0 and class-1 boundaries identical, so
// boundary_mask = 2*b', b' in {0,1}; loss = 4/N * popcount(bp' XOR bg') after
// remove_long_lines — exact integers. Row removal (original row sums) then
// column removal (on row-masked bits) matches reference sequential order.
// -inf padding == window restriction == index CLAMP for max/min pooling
// (clamped duplicate is an in-window value): applied vertically AND
// horizontally, fully branchless.
//
// K1 hot loop is VMEM+VALU ONLY: the horizontal halo comes from two extra
// clamped scalar dword loads per row (same cachelines as the float4), NOT
// from __shfl/ds_bpermute — removing all lgkmcnt stalls from the row chain.

__global__ __launch_bounds__(256, 6) void boundary_bits_kernel(
    const float* __restrict__ seg, const float* __restrict__ gt,
    uint64_t* __restrict__ bits,
    unsigned long long* __restrict__ counter)
{
    if (blockIdx.x == 0 && threadIdx.x == 0) *counter = 0ull;

    const int lane  = threadIdx.x & 63;
    const int wid   = blockIdx.x * 4 + (threadIdx.x >> 6); // 8192 waves
    const int z     = wid >> 12;          // input select
    const int b     = (wid >> 6) & 63;    // batch
    const int strip = (wid >> 1) & 31;    // 16-row strip
    const int half  = wid & 1;            // left/right 256 cols
    const int r0    = strip * RPW;
    const int c0    = half * 256;

    const float* img = (z ? gt : seg) + (size_t)b * HH * WW;
    uint64_t* brow = bits + ((size_t)z * BB + b) * HH * 8 + 4 * half;

    const int j0 = c0 + lane * 4;                       // this lane's first col
    const int jl = (j0 == 0) ? 0 : j0 - 1;              // clamped left-halo col
    const int jr = (j0 + 4 > WW - 1) ? WW - 1 : j0 + 4; // clamped right-halo col

    float4 qv[4];          // 4-deep row queue: main 4 cols
    float  ql[4], qr[4];   // halo cols (clamped)

    auto issue = [&](int slot, int g) {
        int gc = g < 0 ? 0 : (g > HH - 1 ? HH - 1 : g); // vertical clamp
        const float* rp = img + (size_t)gc * WW;
        qv[slot] = *(const float4*)(rp + j0);
        ql[slot] = rp[jl];
        qr[slot] = rp[jr];
    };

    float hmx[3][4], hmn[3][4];

    auto digest = [&](int hs, int qs) {
        float4 v = qv[qs];
        float e0 = ql[qs], e1 = v.x, e2 = v.y, e3 = v.z, e4 = v.w, e5 = qr[qs];
        hmx[hs][0] = fmaxf(fmaxf(e0, e1), e2);
        hmx[hs][1] = fmaxf(fmaxf(e1, e2), e3);
        hmx[hs][2] = fmaxf(fmaxf(e2, e3), e4);
        hmx[hs][3] = fmaxf(fmaxf(e3, e4), e5);
        hmn[hs][0] = fminf(fminf(e0, e1), e2);
        hmn[hs][1] = fminf(fminf(e1, e2), e3);
        hmn[hs][2] = fminf(fminf(e2, e3), e4);
        hmn[hs][3] = fminf(fminf(e3, e4), e5);
    };

    // prologue: fill queue with rows r0-1 .. r0+2, digest the first two
    issue(0, r0 - 1);
    issue(1, r0);
    issue(2, r0 + 1);
    issue(3, r0 + 2);
    digest(0, 0);   // row r0-1
    digest(1, 1);   // row r0

    #pragma unroll
    for (int q = 0; q < RPW; ++q) {
        const int sP = q % 3, sC = (q + 1) % 3, sN = (q + 2) % 3;
        digest(sN, (q + 2) & 3);        // row r0+q+1 (loaded >=2 iters ago)
        issue(q & 3, r0 + q + 3);       // prefetch row r0+q+3 (slot free since q-2)
        uint64_t m0, m1, m2, m3;
        {
            float wmax, wmin;
            wmax = fmaxf(fmaxf(hmx[sP][0], hmx[sC][0]), hmx[sN][0]);
            wmin = fminf(fminf(hmn[sP][0], hmn[sC][0]), hmn[sN][0]);
            m0 = __ballot(wmax - wmin > 0.5f);
            wmax = fmaxf(fmaxf(hmx[sP][1], hmx[sC][1]), hmx[sN][1]);
            wmin = fminf(fminf(hmn[sP][1], hmn[sC][1]), hmn[sN][1]);
            m1 = __ballot(wmax - wmin > 0.5f);
            wmax = fmaxf(fmaxf(hmx[sP][2], hmx[sC][2]), hmx[sN][2]);
            wmin = fminf(fminf(hmn[sP][2], hmn[sC][2]), hmn[sN][2]);
            m2 = __ballot(wmax - wmin > 0.5f);
            wmax = fmaxf(fmaxf(hmx[sP][3], hmx[sC][3]), hmx[sN][3]);
            wmin = fminf(fminf(hmn[sP][3], hmn[sC][3]), hmn[sN][3]);
            m3 = __ballot(wmax - wmin > 0.5f);
        }
        uint64_t mv = m0;
        mv = (lane == 1) ? m1 : mv;
        mv = (lane == 2) ? m2 : mv;
        mv = (lane == 3) ? m3 : mv;
        if (lane < 4) brow[(size_t)(r0 + q) * 8 + lane] = mv;
    }
}

__global__ __launch_bounds__(512) void colxor_kernel(
    const uint64_t* __restrict__ bits,
    unsigned long long* __restrict__ counter)
{
    const int b    = blockIdx.x;
    const int tid  = threadIdx.x;          // = row
    const int wave = tid >> 6, lane = tid & 63;

    __shared__ uint64_t w0T[8][HH];        // [word][row]
    __shared__ uint64_t w1T[8][HH];
    __shared__ unsigned long long cmask[2][8];
    __shared__ int red[8];

    // phase A: row loads (coalesced 64B x2 per thread), rowhit, mask, stash
    const uint64_t* bp = bits + ((size_t)0 * BB + b) * HH * 8 + (size_t)tid * 8;
    const uint64_t* bg = bits + ((size_t)1 * BB + b) * HH * 8 + (size_t)tid * 8;
    uint64_t r0v[8], r1v[8];
    int s0 = 0, s1 = 0;
    #pragma unroll
    for (int i = 0; i < 8; ++i) { r0v[i] = bp[i]; s0 += (int)__popcll(r0v[i]); }
    #pragma unroll
    for (int i = 0; i < 8; ++i) { r1v[i] = bg[i]; s1 += (int)__popcll(r1v[i]); }
    const bool h0 = (s0 >= 300), h1 = (s1 >= 300);
    #pragma unroll
    for (int i = 0; i < 8; ++i) {
        r0v[i] = h0 ? 0ull : r0v[i];
        r1v[i] = h1 ? 0ull : r1v[i];
        w0T[i][tid] = r0v[i];
        w1T[i][tid] = r1v[i];
    }
    __syncthreads();

    // phase B: wave w owns word w; ballot-transpose colsums over 512 rows
    int c0n = 0, c1n = 0;
    #pragma unroll
    for (int k = 0; k < 8; ++k) {
        uint64_t wa = w0T[wave][k * 64 + lane];
        uint64_t wb = w1T[wave][k * 64 + lane];
        #pragma unroll
        for (int c = 0; c < 64; ++c) {
            int pa = (int)__popcll(__ballot((wa >> c) & 1ull));
            int pb = (int)__popcll(__ballot((wb >> c) & 1ull));
            if (lane == c) { c0n += pa; c1n += pb; }
        }
    }
    unsigned long long km0 = __ballot(c0n < 300);
    unsigned long long km1 = __ballot(c1n < 300);
    if (lane == 0) { cmask[0][wave] = km0; cmask[1][wave] = km1; }
    __syncthreads();

    // phase C: masked XOR popcount from registers
    int cnt = 0;
    #pragma unroll
    for (int w = 0; w < 8; ++w)
        cnt += (int)__popcll((r0v[w] & cmask[0][w]) ^ (r1v[w] & cmask[1][w]));
    #pragma unroll
    for (int off = 32; off; off >>= 1) cnt += __shfl_down(cnt, off);
    if (lane == 0) red[wave] = cnt;
    __syncthreads();
    if (tid == 0) {
        int s = 0;
        #pragma unroll
        for (int v = 0; v < 8; ++v) s += red[v];
        atomicAdd(counter, (unsigned long long)s);
    }
}

__global__ void finalize_kernel(const unsigned long long* __restrict__ counter,
                                float* __restrict__ out)
{
    if (threadIdx.x == 0 && blockIdx.x == 0) {
        double v = (double)(*counter) * (4.0 / 16777216.0); // 4/N, N = 64*512*512
        out[0] = (float)v;
    }
}

extern "C" void kernel_launch(void* const* d_in, const int* in_sizes, int n_in,
                              void* d_out, int out_size, void* d_ws, size_t ws_size,
                              hipStream_t stream) {
    const float* seg = (const float*)d_in[0];
    const float* gt  = (const float*)d_in[1];
    float* out = (float*)d_out;

    uint8_t* ws = (uint8_t*)d_ws;
    const size_t bits_bytes = (size_t)2 * BB * HH * 8 * sizeof(uint64_t); // 4 MB
    uint64_t* bits = (uint64_t*)ws;
    unsigned long long* counter = (unsigned long long*)(ws + bits_bytes);

    // K1: 2 inputs * 64 batches * 32 strips * 2 halves = 8192 waves / 4 per block
    boundary_bits_kernel<<<2048, 256, 0, stream>>>(seg, gt, bits, counter);
    // K2: one block per batch (rowhit + colmask + XOR count fused)
    colxor_kernel<<<BB, 512, 0, stream>>>(bits, counter);
    finalize_kernel<<<1, 1, 0, stream>>>(counter, out);
}

// Round 9
// 166.735 us; speedup vs baseline: 1.2648x; 1.0063x over previous
//
#include <hip/hip_runtime.h>
#include <cstdint>
#include <cstddef>

#define HH 512
#define WW 512
#define BB 64
#define RPW 16            // output rows per wave-strip; wave covers 256 cols
#define NROWS (RPW + 2)   // input rows incl. vertical halo

// ws layout:
//   bits   : uint64[2][BB][HH][8]   = 4 MB, UNMASKED boundary bits.
//   Column<->bit mapping (self-consistent K1/K2): word W = 4*half + c (c=0..3),
//   bit k of word W = boundary at col 256*half + 4*k + c.
//   counter: unsigned long long
//
// Algebra: binary masks -> class-0 and class-1 boundaries identical, so
// boundary_mask = 2*b', b' in {0,1}; loss = 4/N * popcount(bp' XOR bg') after
// remove_long_lines — exact integers. Row removal (original row sums) then
// column removal (on row-masked bits) matches reference sequential order.
// -inf padding == window restriction == index CLAMP for max/min pooling.
//
// K1 uses inline-asm loads: hipcc's register-pressure scheduler sinks plain
// loads to their uses (R7/R8: VGPR collapsed to 28-32, MLP~3). asm volatile
// pins all 54 loads in flight before one manual s_waitcnt vmcnt(0) +
// sched_barrier(0) (rule #18: the barrier stops VALU hoisting past the wait).

__global__ __launch_bounds__(256, 3) void boundary_bits_kernel(
    const float* __restrict__ seg, const float* __restrict__ gt,
    uint64_t* __restrict__ bits,
    unsigned long long* __restrict__ counter)
{
    if (blockIdx.x == 0 && threadIdx.x == 0) *counter = 0ull;

    const int lane  = threadIdx.x & 63;
    const int wid   = blockIdx.x * 4 + (threadIdx.x >> 6); // 8192 waves
    const int z     = wid >> 12;          // input select
    const int b     = (wid >> 6) & 63;    // batch
    const int strip = (wid >> 1) & 31;    // 16-row strip
    const int half  = wid & 1;            // left/right 256 cols
    const int r0    = strip * RPW;
    const int c0    = half * 256;

    const float* img = (z ? gt : seg) + (size_t)b * HH * WW;
    uint64_t* brow = bits + ((size_t)z * BB + b) * HH * 8 + 4 * half;

    const int j0 = c0 + lane * 4;                       // this lane's first col
    const int jl = (j0 == 0) ? 0 : j0 - 1;              // clamped left-halo col
    const int jr = (j0 + 4 > WW - 1) ? WW - 1 : j0 + 4; // clamped right-halo col

    float4 qv[NROWS];          // main 4 cols per input row
    float  ql[NROWS], qr[NROWS];

    // ---- issue ALL strip loads, pinned in program order ----
    #pragma unroll
    for (int rr = 0; rr < NROWS; ++rr) {
        int g  = r0 - 1 + rr;
        int gc = g < 0 ? 0 : (g > HH - 1 ? HH - 1 : g); // vertical clamp
        const float* rp = img + (size_t)gc * WW;
        asm volatile("global_load_dwordx4 %0, %1, off" : "=v"(qv[rr]) : "v"(rp + j0));
        asm volatile("global_load_dword %0, %1, off"   : "=v"(ql[rr]) : "v"(rp + jl));
        asm volatile("global_load_dword %0, %1, off"   : "=v"(qr[rr]) : "v"(rp + jr));
    }
    asm volatile("s_waitcnt vmcnt(0)" ::: "memory");
    __builtin_amdgcn_sched_barrier(0);

    // ---- digest 16 output rows from registers ----
    #pragma unroll
    for (int q = 0; q < RPW; ++q) {
        // h-extremes recomputed per row (v_max3/v_min3), no extra window regs
        float mx[3][4], mn[3][4];
        #pragma unroll
        for (int s = 0; s < 3; ++s) {
            const int rs = q + s;
            float e0 = ql[rs], e1 = qv[rs].x, e2 = qv[rs].y,
                  e3 = qv[rs].z, e4 = qv[rs].w, e5 = qr[rs];
            mx[s][0] = fmaxf(fmaxf(e0, e1), e2);
            mx[s][1] = fmaxf(fmaxf(e1, e2), e3);
            mx[s][2] = fmaxf(fmaxf(e2, e3), e4);
            mx[s][3] = fmaxf(fmaxf(e3, e4), e5);
            mn[s][0] = fminf(fminf(e0, e1), e2);
            mn[s][1] = fminf(fminf(e1, e2), e3);
            mn[s][2] = fminf(fminf(e2, e3), e4);
            mn[s][3] = fminf(fminf(e3, e4), e5);
        }
        uint64_t m0, m1, m2, m3;
        {
            float wmax, wmin;
            wmax = fmaxf(fmaxf(mx[0][0], mx[1][0]), mx[2][0]);
            wmin = fminf(fminf(mn[0][0], mn[1][0]), mn[2][0]);
            m0 = __ballot(wmax - wmin > 0.5f);
            wmax = fmaxf(fmaxf(mx[0][1], mx[1][1]), mx[2][1]);
            wmin = fminf(fminf(mn[0][1], mn[1][1]), mn[2][1]);
            m1 = __ballot(wmax - wmin > 0.5f);
            wmax = fmaxf(fmaxf(mx[0][2], mx[1][2]), mx[2][2]);
            wmin = fminf(fminf(mn[0][2], mn[1][2]), mn[2][2]);
            m2 = __ballot(wmax - wmin > 0.5f);
            wmax = fmaxf(fmaxf(mx[0][3], mx[1][3]), mx[2][3]);
            wmin = fminf(fminf(mn[0][3], mn[1][3]), mn[2][3]);
            m3 = __ballot(wmax - wmin > 0.5f);
        }
        uint64_t mv = m0;
        mv = (lane == 1) ? m1 : mv;
        mv = (lane == 2) ? m2 : mv;
        mv = (lane == 3) ? m3 : mv;
        if (lane < 4) brow[(size_t)(r0 + q) * 8 + lane] = mv;
    }
}

__global__ __launch_bounds__(512) void colxor_kernel(
    const uint64_t* __restrict__ bits,
    unsigned long long* __restrict__ counter)
{
    const int b    = blockIdx.x;
    const int tid  = threadIdx.x;          // = row
    const int wave = tid >> 6, lane = tid & 63;

    __shared__ uint64_t w0T[8][HH];        // [word][row]
    __shared__ uint64_t w1T[8][HH];
    __shared__ unsigned long long cmask[2][8];
    __shared__ int red[8];

    // phase A: row loads (coalesced 64B x2 per thread), rowhit, mask, stash
    const uint64_t* bp = bits + ((size_t)0 * BB + b) * HH * 8 + (size_t)tid * 8;
    const uint64_t* bg = bits + ((size_t)1 * BB + b) * HH * 8 + (size_t)tid * 8;
    uint64_t r0v[8], r1v[8];
    int s0 = 0, s1 = 0;
    #pragma unroll
    for (int i = 0; i < 8; ++i) { r0v[i] = bp[i]; s0 += (int)__popcll(r0v[i]); }
    #pragma unroll
    for (int i = 0; i < 8; ++i) { r1v[i] = bg[i]; s1 += (int)__popcll(r1v[i]); }
    const bool h0 = (s0 >= 300), h1 = (s1 >= 300);
    #pragma unroll
    for (int i = 0; i < 8; ++i) {
        r0v[i] = h0 ? 0ull : r0v[i];
        r1v[i] = h1 ? 0ull : r1v[i];
        w0T[i][tid] = r0v[i];
        w1T[i][tid] = r1v[i];
    }
    __syncthreads();

    // phase B: wave w owns word w; ballot-transpose colsums over 512 rows
    int c0n = 0, c1n = 0;
    #pragma unroll
    for (int k = 0; k < 8; ++k) {
        uint64_t wa = w0T[wave][k * 64 + lane];
        uint64_t wb = w1T[wave][k * 64 + lane];
        #pragma unroll
        for (int c = 0; c < 64; ++c) {
            int pa = (int)__popcll(__ballot((wa >> c) & 1ull));
            int pb = (int)__popcll(__ballot((wb >> c) & 1ull));
            if (lane == c) { c0n += pa; c1n += pb; }
        }
    }
    unsigned long long km0 = __ballot(c0n < 300);
    unsigned long long km1 = __ballot(c1n < 300);
    if (lane == 0) { cmask[0][wave] = km0; cmask[1][wave] = km1; }
    __syncthreads();

    // phase C: masked XOR popcount from registers
    int cnt = 0;
    #pragma unroll
    for (int w = 0; w < 8; ++w)
        cnt += (int)__popcll((r0v[w] & cmask[0][w]) ^ (r1v[w] & cmask[1][w]));
    #pragma unroll
    for (int off = 32; off; off >>= 1) cnt += __shfl_down(cnt, off);
    if (lane == 0) red[wave] = cnt;
    __syncthreads();
    if (tid == 0) {
        int s = 0;
        #pragma unroll
        for (int v = 0; v < 8; ++v) s += red[v];
        atomicAdd(counter, (unsigned long long)s);
    }
}

__global__ void finalize_kernel(const unsigned long long* __restrict__ counter,
                                float* __restrict__ out)
{
    if (threadIdx.x == 0 && blockIdx.x == 0) {
        double v = (double)(*counter) * (4.0 / 16777216.0); // 4/N, N = 64*512*512
        out[0] = (float)v;
    }
}

extern "C" void kernel_launch(void* const* d_in, const int* in_sizes, int n_in,
                              void* d_out, int out_size, void* d_ws, size_t ws_size,
                              hipStream_t stream) {
    const float* seg = (const float*)d_in[0];
    const float* gt  = (const float*)d_in[1];
    float* out = (float*)d_out;

    uint8_t* ws = (uint8_t*)d_ws;
    const size_t bits_bytes = (size_t)2 * BB * HH * 8 * sizeof(uint64_t); // 4 MB
    uint64_t* bits = (uint64_t*)ws;
    unsigned long long* counter = (unsigned long long*)(ws + bits_bytes);

    // K1: 2 inputs * 64 batches * 32 strips * 2 halves = 8192 waves / 4 per block
    boundary_bits_kernel<<<2048, 256, 0, stream>>>(seg, gt, bits, counter);
    // K2: one block per batch (rowhit + colmask + XOR count fused)
    colxor_kernel<<<BB, 512, 0, stream>>>(bits, counter);
    finalize_kernel<<<1, 1, 0, stream>>>(counter, out);
}